// Round 1
// baseline (153.466 us; speedup 1.0000x reference)
//
#include <hip/hip_runtime.h>

// BlockwiseQuantizationOptim — MI355X (gfx950)
// weight [4096,2048] f32 -> out [4096,2048] f32 + total_entropy scalar.
// 512 quant blocks of 128x128; 31-bin soft quantization (T=100) + entropy
// over per-(block, column, bin) soft-assignment mass.

#define RR 4096
#define CC 2048
#define BSZ 128
#define NBC 16          // CC/BSZ
#define NBINS 31
#define EPS 1e-6f

__global__ void __launch_bounds__(512)
bq_kernel(const float* __restrict__ weight,
          const float* __restrict__ w_min,
          const float* __restrict__ w_max,
          const float* __restrict__ bins,
          float* __restrict__ out,
          float* __restrict__ ent_out)
{
    const int n   = blockIdx.x;      // quant block id, 0..511
    const int br  = n >> 4;          // n / NBC
    const int bc  = n & 15;          // n % NBC
    const int tid = threadIdx.x;     // 0..511
    const int j   = tid & (BSZ - 1); // column within block
    const int q   = tid >> 7;        // row-quarter 0..3, 32 rows each

    __shared__ float smass[BSZ][NBINS + 2]; // stride 33 -> conflict-free
    __shared__ float sred[BSZ];
    __shared__ float swred[8];
    __shared__ float stot;

    // zero the mass accumulator tile
    for (int idx = tid; idx < BSZ * (NBINS + 2); idx += 512)
        (&smass[0][0])[idx] = 0.0f;
    __syncthreads();

    // wave-uniform per-block scalars
    const float wmn      = w_min[n];
    const float wmx      = w_max[n];
    const float wmin_c   = fminf(wmn, wmx - EPS);
    const float wmax_c   = fmaxf(wmx, wmin_c + EPS);
    const float span     = wmax_c - wmin_c;
    const float inv_span = 1.0f / (span + EPS);

    float b[NBINS];
#pragma unroll
    for (int l = 0; l < NBINS; ++l) b[l] = bins[n * NBINS + l];

    float mass[NBINS];
#pragma unroll
    for (int l = 0; l < NBINS; ++l) mass[l] = 0.0f;

    const size_t base = (size_t)(br * BSZ + q * 32) * CC + (size_t)bc * BSZ + j;
    const float* wp = weight + base;
    float*       op = out + base;

    const float nT = -100.0f;

    for (int i = 0; i < 32; ++i) {
        float w  = wp[(size_t)i * CC];
        float wn = (w - wmin_c) * inv_span;

        float ev[NBINS];
        float sacc[4] = {0.f, 0.f, 0.f, 0.f};
        float qacc[4] = {0.f, 0.f, 0.f, 0.f};
#pragma unroll
        for (int l = 0; l < NBINS; ++l) {
            float ad = fabsf(wn - b[l]);
            float e  = __expf(nT * ad);   // ratios identical to max-subtracted softmax
            ev[l] = e;
            sacc[l & 3] += e;
            qacc[l & 3] = fmaf(e, b[l], qacc[l & 3]);
        }
        float sum  = (sacc[0] + sacc[1]) + (sacc[2] + sacc[3]);
        float wq   = (qacc[0] + qacc[1]) + (qacc[2] + qacc[3]);
        float rsum = 1.0f / sum;

        op[(size_t)i * CC] = fmaf(wq * rsum, span, wmin_c);

#pragma unroll
        for (int l = 0; l < NBINS; ++l)
            mass[l] = fmaf(ev[l], rsum, mass[l]);
    }

    // combine per-thread masses into per-column masses (4 threads/column)
#pragma unroll
    for (int l = 0; l < NBINS; ++l)
        atomicAdd(&smass[j][l], mass[l]);
    __syncthreads();

    // per-column totals
    if (tid < BSZ) {
        float cs = 0.0f;
#pragma unroll
        for (int l = 0; l < NBINS; ++l) cs += smass[tid][l];
        sred[tid] = cs;
    }
    __syncthreads();

    // block total (wave 0)
    if (tid < 64) {
        float v = sred[tid] + sred[tid + 64];
#pragma unroll
        for (int off = 32; off > 0; off >>= 1)
            v += __shfl_down(v, off);
        if (tid == 0) stot = v;
    }
    __syncthreads();

    // entropy partials
    float ent = 0.0f;
    if (tid < BSZ) {
        float rtot = 1.0f / (stot + EPS);
#pragma unroll
        for (int l = 0; l < NBINS; ++l) {
            float p = smass[tid][l] * rtot;
            ent += p * __logf(p + EPS);
        }
    }
    // block reduction of entropy
    float v = ent;
#pragma unroll
    for (int off = 32; off > 0; off >>= 1)
        v += __shfl_down(v, off);
    if ((tid & 63) == 0) swred[tid >> 6] = v;
    __syncthreads();
    if (tid == 0) {
        float t = 0.0f;
#pragma unroll
        for (int k = 0; k < 8; ++k) t += swred[k];
        atomicAdd(ent_out, -t);
    }
}

extern "C" void kernel_launch(void* const* d_in, const int* in_sizes, int n_in,
                              void* d_out, int out_size, void* d_ws, size_t ws_size,
                              hipStream_t stream) {
    const float* weight = (const float*)d_in[0];
    const float* wmin_p = (const float*)d_in[1];
    const float* wmax_p = (const float*)d_in[2];
    const float* bins_p = (const float*)d_in[3];
    float* out = (float*)d_out;
    float* ent = out + (size_t)RR * CC;   // entropy scalar after the 8M outputs

    hipMemsetAsync(ent, 0, sizeof(float), stream);
    bq_kernel<<<dim3(512), dim3(512), 0, stream>>>(weight, wmin_p, wmax_p, bins_p, out, ent);
}